// Round 4
// baseline (122.035 us; speedup 1.0000x reference)
//
#include <hip/hip_runtime.h>
#include <hip/hip_bf16.h>
#include <cstddef>
#include <cstdint>

#define CC   128
#define AD   16
#define VD   64
#define HWN  4096
#define PJ   1024
#define NB   8

typedef short short8 __attribute__((ext_vector_type(8)));
typedef float f32x4  __attribute__((ext_vector_type(4)));
typedef unsigned short u16;

__device__ inline u16 f2bf(float f) {
    __hip_bfloat16 h = __float2bfloat16(f);
    union { __hip_bfloat16 h; u16 u; } c; c.h = h; return c.u;
}
__device__ inline unsigned pk2(float a, float b) {
    __hip_bfloat162 h = __float22bfloat162_rn(make_float2(a, b));
    union { __hip_bfloat162 h; unsigned u; } c; c.h = h; return c.u;
}
__device__ inline float bf16f(u16 v) {
    union { unsigned u; float f; } a; a.u = ((unsigned)v) << 16;
    return a.f;
}

// XOR-swizzled physical element index for bf16 LDS tiles (8-elem blocks):
// conflict-free ds_read_b128 MFMA fragment reads.
__device__ inline int ph128(int r, int c) { return r * 128 + ((((c >> 3) ^ (r & 7)) << 3) | (c & 7)); }
__device__ inline int ph64 (int r, int c) { return r * 64  + ((((c >> 3) ^ (r & 7)) << 3) | (c & 7)); }

// async global->LDS, 16B per lane. LDS dest must be wave-uniform base + lane*16
// (our layouts are lane-linear by construction; fallback writes same addresses).
__device__ inline void stage16(const u16* g, u16* l) {
#if __has_builtin(__builtin_amdgcn_global_load_lds)
    __builtin_amdgcn_global_load_lds(
        (const __attribute__((address_space(1))) unsigned int*)g,
        (__attribute__((address_space(3))) unsigned int*)l, 16, 0, 0);
#else
    *(uint4*)l = *(const uint4*)g;
#endif
}

// ---------------------------------------------------------------------------
// Kernel 1: QKV projection (MFMA, M=128 pos x K=128 ch x N=96) + 2x2 maxpool
// done ENTIRELY in registers (wave w owns m-tiles {w, w+4} so pool pairs are
// register/lane-local). One barrier. Outputs (bf16):
//   Qp[n][4096][16]
//   Kp[n][j][dsw]            dsw = ((d>>3 ^ j&1)<<3)|(d&7)   (pre-swizzled)
//   Vt2[n][ch][dv][jsw]      ch=j>>7, jsw = ((jl>>3 ^ dv&7)<<3)|(jl&7), jl=j&127
// ---------------------------------------------------------------------------
__global__ __launch_bounds__(256) void k_proj(
    const float* __restrict__ x,
    const float* __restrict__ Wq, const float* __restrict__ bq,
    const float* __restrict__ Wk, const float* __restrict__ bk,
    const float* __restrict__ Wv, const float* __restrict__ bv,
    u16* __restrict__ Qp, u16* __restrict__ Kp, u16* __restrict__ Vt2)
{
    __shared__ __align__(16) u16 xT[128 * 128];   // [pos][ch] ph128
    __shared__ __align__(16) u16 WT[96 * 128];    // [n][ch]   ph128

    const int tile = blockIdx.x, n = blockIdx.y, t = threadIdx.x;
    const int p0 = tile * 128;
    const int l = t & 63, w = t >> 6, g = l >> 4, lm = l & 15;

    // ---- stage x tile: float4 loads (4 pos x 4 ch per iter), cvt_pk -> b64 LDS
    {
        const float* xb = x + (size_t)n * CC * HWN + p0;
#pragma unroll
        for (int it = 0; it < 4; ++it) {
            const int idx = t + 256 * it;
            const int p4 = idx & 31, c4 = idx >> 5;       // c4: 0..31 -> ch = c4*4
            const float* bp = xb + p4 * 4;
            const f32x4 r0 = *(const f32x4*)(bp + (size_t)(c4 * 4 + 0) * HWN);
            const f32x4 r1 = *(const f32x4*)(bp + (size_t)(c4 * 4 + 1) * HWN);
            const f32x4 r2 = *(const f32x4*)(bp + (size_t)(c4 * 4 + 2) * HWN);
            const f32x4 r3 = *(const f32x4*)(bp + (size_t)(c4 * 4 + 3) * HWN);
#pragma unroll
            for (int pp = 0; pp < 4; ++pp) {
                const int pos = p4 * 4 + pp;
                uint2 v;
                v.x = pk2(r0[pp], r1[pp]);
                v.y = pk2(r2[pp], r3[pp]);
                *(uint2*)&xT[pos * 128 + ((((c4 >> 1) ^ (pos & 7)) << 3) | ((c4 & 1) * 4))] = v;
            }
        }
    }
    // ---- stage W^T: rows 0..15 Wq, 16..31 Wk, 32..95 Wv ----
#pragma unroll
    for (int it = 0; it < 2; ++it) {
        const int idx = t + 256 * it;
        const int d4 = idx & 3, ch = idx >> 2;
        float4 v = *(const float4*)(Wq + ch * AD + d4 * 4);
        WT[ph128(d4 * 4 + 0, ch)] = f2bf(v.x);
        WT[ph128(d4 * 4 + 1, ch)] = f2bf(v.y);
        WT[ph128(d4 * 4 + 2, ch)] = f2bf(v.z);
        WT[ph128(d4 * 4 + 3, ch)] = f2bf(v.w);
        v = *(const float4*)(Wk + ch * AD + d4 * 4);
        WT[ph128(16 + d4 * 4 + 0, ch)] = f2bf(v.x);
        WT[ph128(16 + d4 * 4 + 1, ch)] = f2bf(v.y);
        WT[ph128(16 + d4 * 4 + 2, ch)] = f2bf(v.z);
        WT[ph128(16 + d4 * 4 + 3, ch)] = f2bf(v.w);
    }
#pragma unroll
    for (int it = 0; it < 8; ++it) {
        const int idx = t + 256 * it;
        const int d4 = idx & 15, ch = idx >> 4;
        const float4 v = *(const float4*)(Wv + ch * VD + d4 * 4);
        WT[ph128(32 + d4 * 4 + 0, ch)] = f2bf(v.x);
        WT[ph128(32 + d4 * 4 + 1, ch)] = f2bf(v.y);
        WT[ph128(32 + d4 * 4 + 2, ch)] = f2bf(v.z);
        WT[ph128(32 + d4 * 4 + 3, ch)] = f2bf(v.w);
    }
    __syncthreads();

    // ---- MFMA: wave w owns m-tiles {w, w+4} x 6 n-tiles ----
    f32x4 acc[2][6];
#pragma unroll
    for (int i = 0; i < 2; ++i)
#pragma unroll
        for (int j = 0; j < 6; ++j) acc[i][j] = (f32x4){0.f, 0.f, 0.f, 0.f};
#pragma unroll
    for (int ks = 0; ks < 4; ++ks) {
        const short8 a0 = *(const short8*)&xT[ph128(w * 16 + lm,       ks * 32 + g * 8)];
        const short8 a1 = *(const short8*)&xT[ph128((w + 4) * 16 + lm, ks * 32 + g * 8)];
#pragma unroll
        for (int nt = 0; nt < 6; ++nt) {
            const short8 b = *(const short8*)&WT[ph128(nt * 16 + lm, ks * 32 + g * 8)];
            acc[0][nt] = __builtin_amdgcn_mfma_f32_16x16x32_bf16(a0, b, acc[0][nt], 0, 0, 0);
            acc[1][nt] = __builtin_amdgcn_mfma_f32_16x16x32_bf16(a1, b, acc[1][nt], 0, 0, 0);
        }
    }

    // ---- register epilogue (no LDS, no barrier) ----
    // C layout: row = g*4+r (pos within m-tile), col = lm.
    const float bqv = bq[lm], bkv = bk[lm];

    // Q (+bq), nt 0
#pragma unroll
    for (int mi = 0; mi < 2; ++mi) {
        const int mt = w + mi * 4;
#pragma unroll
        for (int r = 0; r < 4; ++r) {
            const int pos = mt * 16 + g * 4 + r;
            Qp[((size_t)n * HWN + p0 + pos) * AD + lm] = f2bf(acc[mi][0][r] + bqv);
        }
    }
    // K pooled (+bk), nt 1: cell a uses regs {2a,2a+1} of both m-tiles
#pragma unroll
    for (int a = 0; a < 2; ++a) {
        const float m = fmaxf(fmaxf(acc[0][1][2 * a], acc[0][1][2 * a + 1]),
                              fmaxf(acc[1][1][2 * a], acc[1][1][2 * a + 1])) + bkv;
        const int j = tile * 32 + w * 8 + g * 2 + a;
        const int dsw = (((lm >> 3) ^ (j & 1)) << 3) | (lm & 7);
        Kp[((size_t)n * PJ + j) * AD + dsw] = f2bf(m);
    }
    // V pooled (+bv), nt 2..5 -> packed u32 store (2 adjacent pooled j)
#pragma unroll
    for (int nt = 0; nt < 4; ++nt) {
        const int dv = nt * 16 + lm;
        const float bvv = bv[dv];
        const float m0 = fmaxf(fmaxf(acc[0][nt + 2][0], acc[0][nt + 2][1]),
                               fmaxf(acc[1][nt + 2][0], acc[1][nt + 2][1])) + bvv;
        const float m1 = fmaxf(fmaxf(acc[0][nt + 2][2], acc[0][nt + 2][3]),
                               fmaxf(acc[1][nt + 2][2], acc[1][nt + 2][3])) + bvv;
        const int jl  = (tile & 3) * 32 + w * 8 + g * 2;          // even
        const int jsw = (((jl >> 3) ^ (dv & 7)) << 3) | (jl & 7);
        *(unsigned*)&Vt2[((((size_t)n * 8 + (tile >> 2)) * VD + dv) << 7) + jsw] = pk2(m0, m1);
    }
}

// ---------------------------------------------------------------------------
// Kernel 2: flash attention + out-proj + residual, all MFMA.
// Grid (64,8), block 256 (4 waves x 16 q). Double-buffered async KV staging:
// loads for chunk ch+1 issued BEFORE computing chunk ch -> 1 barrier/chunk.
// ---------------------------------------------------------------------------
__global__ __launch_bounds__(256) void k_attn(
    const float* __restrict__ x,
    const u16* __restrict__ Qp, const u16* __restrict__ Kp, const u16* __restrict__ Vt2,
    const float* __restrict__ Wo, const float* __restrict__ bo,
    const float* __restrict__ gma,
    float* __restrict__ out)
{
    __shared__ __align__(16) u16 KV[2][10240];   // per buf: K 2048 elems | V 8192 elems
    __shared__ __align__(16) u16 PB[4 * 2048];   // per-wave P; reused as O^T

    const int n = blockIdx.y, t = threadIdx.x;
    const int q0b = blockIdx.x * 64;
    const int l = t & 63, w = t >> 6, g = l >> 4, lm = l & 15;

    // Q A-frag (g>=2 lanes are the K=16..31 zero pad)
    short8 qf = {0, 0, 0, 0, 0, 0, 0, 0};
    if (g < 2)
        qf = *(const short8*)(Qp + ((size_t)n * HWN + q0b + w * 16 + lm) * AD + g * 8);

    // prefetch residual x (consumed at the very end; hides L3/HBM latency)
    float xr[8][4];
#pragma unroll
    for (int mt = 0; mt < 8; ++mt)
#pragma unroll
        for (int r = 0; r < 4; ++r)
            xr[mt][r] = x[((size_t)n * CC + mt * 16 + g * 4 + r) * HWN + q0b + w * 16 + lm];

    const u16* Kg = Kp  + (size_t)n * PJ * AD;        // chunk ch at + ch*2048
    const u16* Vg = Vt2 + (size_t)n * 8 * VD * 128;   // chunk ch at + ch*8192

    // stage chunk 0
    {
        stage16(Kg + t * 8, &KV[0][t * 8]);
#pragma unroll
        for (int i = 0; i < 4; ++i)
            stage16(Vg + ((w * 4 + i) * 64 + l) * 8, &KV[0][2048 + (w * 4 + i) * 512 + l * 8]);
    }
    __syncthreads();

    f32x4 O[4];
#pragma unroll
    for (int i = 0; i < 4; ++i) O[i] = (f32x4){0.f, 0.f, 0.f, 0.f};
    float mr[4] = {-1e30f, -1e30f, -1e30f, -1e30f};
    float lr[4] = {0.f, 0.f, 0.f, 0.f};
    u16* Pl = PB + w * 2048;

    for (int ch = 0; ch < 8; ++ch) {
        const u16* Kl = KV[ch & 1];
        const u16* Vl = KV[ch & 1] + 2048;

        // issue async loads for next chunk BEFORE compute (overlap)
        if (ch < 7) {
            const int b = (ch + 1) & 1;
            const size_t ko = (size_t)(ch + 1) * 2048, vo = (size_t)(ch + 1) * 8192;
            stage16(Kg + ko + t * 8, &KV[b][t * 8]);
#pragma unroll
            for (int i = 0; i < 4; ++i)
                stage16(Vg + vo + ((w * 4 + i) * 64 + l) * 8,
                        &KV[b][2048 + (w * 4 + i) * 512 + l * 8]);
        }

        // ---- scores: 8 j-tiles of 16, K=32 (d zero-padded) ----
        f32x4 S[8];
#pragma unroll
        for (int jt = 0; jt < 8; ++jt) {
            short8 kb = {0, 0, 0, 0, 0, 0, 0, 0};
            if (g < 2) {
                const int j = jt * 16 + lm;
                kb = *(const short8*)&Kl[(j * 2 + (g ^ (j & 1))) * 8];
            }
            const f32x4 z = (f32x4){0.f, 0.f, 0.f, 0.f};
            S[jt] = __builtin_amdgcn_mfma_f32_16x16x32_bf16(qf, kb, z, 0, 0, 0);
        }

        // ---- online softmax (C layout: row=g*4+r, col=jt*16+lm) ----
#pragma unroll
        for (int r = 0; r < 4; ++r) {
            float cm = S[0][r];
#pragma unroll
            for (int jt = 1; jt < 8; ++jt) cm = fmaxf(cm, S[jt][r]);
            cm = fmaxf(cm, __shfl_xor(cm, 1));
            cm = fmaxf(cm, __shfl_xor(cm, 2));
            cm = fmaxf(cm, __shfl_xor(cm, 4));
            cm = fmaxf(cm, __shfl_xor(cm, 8));
            const float nm = fmaxf(mr[r], cm);
            const float al = __expf(mr[r] - nm);
            mr[r] = nm;
            const int row = g * 4 + r;
            float sum = 0.f;
#pragma unroll
            for (int jt = 0; jt < 8; ++jt) {
                const float p = __expf(S[jt][r] - nm);
                sum += p;
                Pl[ph128(row, jt * 16 + lm)] = f2bf(p);
            }
            sum += __shfl_xor(sum, 1);
            sum += __shfl_xor(sum, 2);
            sum += __shfl_xor(sum, 4);
            sum += __shfl_xor(sum, 8);
            lr[r] = lr[r] * al + sum;
            O[0][r] *= al; O[1][r] *= al; O[2][r] *= al; O[3][r] *= al;
        }

        // ---- P @ V ----
#pragma unroll
        for (int ks = 0; ks < 4; ++ks) {
            const short8 pf = *(const short8*)&Pl[ph128(lm, ks * 32 + g * 8)];
#pragma unroll
            for (int dt = 0; dt < 4; ++dt) {
                const short8 vf = *(const short8*)&Vl[ph128(dt * 16 + lm, ks * 32 + g * 8)];
                O[dt] = __builtin_amdgcn_mfma_f32_16x16x32_bf16(pf, vf, O[dt], 0, 0, 0);
            }
        }
        __syncthreads();   // drains next-chunk loads; protects buffer reuse
    }

    // ---- normalize, O^T -> per-wave LDS (B-frag for out-proj) ----
    u16* Ol = Pl;
#pragma unroll
    for (int r = 0; r < 4; ++r) {
        const float inv = 1.f / lr[r];
        const int row = g * 4 + r;
#pragma unroll
        for (int dt = 0; dt < 4; ++dt)
            Ol[ph64(row, dt * 16 + lm)] = f2bf(O[dt][r] * inv);
    }
    // ---- stage WoT[c][dv] into KV[0] (dead; all waves past last barrier) ----
    u16* WoTl = (u16*)KV;
#pragma unroll
    for (int it = 0; it < 8; ++it) {
        const int idx = t + 256 * it;
        const int c4 = idx & 31, dv = idx >> 5;
        const float4 v = *(const float4*)(Wo + dv * CC + c4 * 4);
        WoTl[ph64(c4 * 4 + 0, dv)] = f2bf(v.x);
        WoTl[ph64(c4 * 4 + 1, dv)] = f2bf(v.y);
        WoTl[ph64(c4 * 4 + 2, dv)] = f2bf(v.z);
        WoTl[ph64(c4 * 4 + 3, dv)] = f2bf(v.w);
    }
    __syncthreads();

    // ---- out-proj: D[c][q] = WoT(c,dv) @ O^T(dv,q); residual from prefetch ----
    const float gm = gma[0];
#pragma unroll
    for (int mt = 0; mt < 8; ++mt) {
        f32x4 D = (f32x4){0.f, 0.f, 0.f, 0.f};
#pragma unroll
        for (int ks = 0; ks < 2; ++ks) {
            const short8 af = *(const short8*)&WoTl[ph64(mt * 16 + lm, ks * 32 + g * 8)];
            const short8 bf = *(const short8*)&Ol[ph64(lm, ks * 32 + g * 8)];
            D = __builtin_amdgcn_mfma_f32_16x16x32_bf16(af, bf, D, 0, 0, 0);
        }
#pragma unroll
        for (int r = 0; r < 4; ++r) {
            const int c = mt * 16 + g * 4 + r;
            const size_t off = ((size_t)n * CC + c) * HWN + q0b + w * 16 + lm;
            out[off] = xr[mt][r] + gm * (D[r] + bo[c]);
        }
    }
}

extern "C" void kernel_launch(void* const* d_in, const int* in_sizes, int n_in,
                              void* d_out, int out_size, void* d_ws, size_t ws_size,
                              hipStream_t stream) {
    const float* x     = (const float*)d_in[0];
    const float* Wq    = (const float*)d_in[1];
    const float* bq    = (const float*)d_in[2];
    const float* Wk    = (const float*)d_in[3];
    const float* bk    = (const float*)d_in[4];
    const float* Wv    = (const float*)d_in[5];
    const float* bv    = (const float*)d_in[6];
    const float* Wo    = (const float*)d_in[7];
    const float* bo    = (const float*)d_in[8];
    const float* gamma = (const float*)d_in[9];
    float* out = (float*)d_out;

    u16* Qp  = (u16*)d_ws;                         // 8*4096*16 bf16 = 1 MB
    u16* Kp  = Qp + (size_t)NB * HWN * AD;         // 8*1024*16 bf16 = 256 KB
    u16* Vt2 = Kp + (size_t)NB * PJ * AD;          // 8*8*64*128 bf16 = 1 MB

    k_proj<<<dim3(32, NB), 256, 0, stream>>>(x, Wq, bq, Wk, bk, Wv, bv, Qp, Kp, Vt2);
    k_attn<<<dim3(64, NB), 256, 0, stream>>>(x, Qp, Kp, Vt2, Wo, bo, gamma, out);
}